// Round 2
// 1093.901 us; speedup vs baseline: 1.0383x; 1.0383x over previous
//
#include <hip/hip_runtime.h>

#define NPTS 80000
#define MPTS 150000
#define NDPTS 10000
#define KOFF 27
#define C3 16
#define CP 259
#define C2 64
#define CM 80
#define CO 96

typedef __attribute__((ext_vector_type(8))) short short8;
typedef __attribute__((ext_vector_type(4))) float f32x4;

__device__ inline short bf16r(float f) {
  union { float f; unsigned u; } x{f};
  unsigned r = (x.u + 0x7fffu + ((x.u >> 16) & 1u)) >> 16;
  return (short)r;
}

// ---------------------------------------------------------------------------
// Weight prep: W[k][ci][n] fp32 -> fragment-ordered bf16
// WbfF[((k*KC+q)*NT+t)*512 + lane*8 + j], B-frag element:
// ci = q*32 + (lane>>4)*8 + j, n = t*16 + (lane&15); ci >= CIN zero-padded.
// ---------------------------------------------------------------------------
__global__ void wfrag_kernel(const float* __restrict__ W, short* __restrict__ WbfF,
                             int CIN, int COUT_, int KC) {
  const int NT = COUT_ / 16;
  int i = blockIdx.x * 256 + threadIdx.x;
  int total = KOFF * KC * NT * 512;
  if (i >= total) return;
  int j = i & 7, lane = (i >> 3) & 63;
  int rest = i >> 9;
  int t = rest % NT; rest /= NT;
  int q = rest % KC;
  int k = rest / KC;
  int ci = q * 32 + (lane >> 4) * 8 + j;
  int n = t * 16 + (lane & 15);
  float v = (ci < CIN) ? W[((size_t)k * CIN + ci) * COUT_ + n] : 0.f;
  WbfF[i] = bf16r(v);
}

// ---------------------------------------------------------------------------
// Wp prep: fp32 [259][64] -> bf16 fragment-ordered [q][t][lane][8], K->288.
// ---------------------------------------------------------------------------
__global__ void wpfrag_kernel(const float* __restrict__ Wp, short* __restrict__ WpF) {
  int i = blockIdx.x * 256 + threadIdx.x;
  if (i >= 9 * 4 * 64 * 8) return;
  int j = i & 7, lane = (i >> 3) & 63, t = (i >> 9) & 3, q = i >> 11;
  int k = q * 32 + (lane >> 4) * 8 + j;
  int n = t * 16 + (lane & 15);
  WpF[i] = (k < CP) ? bf16r(Wp[(size_t)k * C2 + n]) : (short)0;
}

// ---------------------------------------------------------------------------
// Kernel 1: conv3d (16->16) + bn_relu -> y3d fp32, mix[:, :16], mixbf[:, :16].
// ---------------------------------------------------------------------------
__global__ __launch_bounds__(256) void conv3d_bnrelu_kernel(
    const float* __restrict__ x3d, const int* __restrict__ nbr,
    const float* __restrict__ W3d, const float* __restrict__ g3d,
    const float* __restrict__ b3d, float* __restrict__ y3d,
    float* __restrict__ mix, short* __restrict__ mixbf)
{
  __shared__ float wS[KOFF * C3 * C3];
  __shared__ float fS[16][C3];
  const int tid = threadIdx.x;
  const int base = blockIdx.x * 16;
  for (int e = tid; e < KOFF * C3 * C3; e += 256) wS[e] = W3d[e];
  const int r = tid >> 4, c = tid & 15;
  const int row = base + r;
  float acc = 0.f;
  for (int k = 0; k < KOFF; ++k) {
    int idx = nbr[row * KOFF + k];
    float fv = (idx >= 0) ? x3d[idx * C3 + c] : 0.f;
    __syncthreads();
    fS[r][c] = fv;
    __syncthreads();
    const float* wk = &wS[k * C3 * C3];
    #pragma unroll
    for (int ci = 0; ci < C3; ++ci)
      acc = fmaf(fS[r][ci], wk[ci * C3 + c], acc);
  }
  float v = fmaxf(fmaf(acc, g3d[c], b3d[c]), 0.f);
  y3d[row * C3 + c] = v;
  mix[row * CM + c] = v;
  mixbf[row * CM + c] = bf16r(v);
}

// ---------------------------------------------------------------------------
// Kernel 2: gate/cross fusion (unchanged).
// ---------------------------------------------------------------------------
__global__ __launch_bounds__(256) void gate_cross_mfma_kernel(
    const float* __restrict__ y3d, const float* __restrict__ f2d,
    const int* __restrict__ nn_idx,
    const float* __restrict__ Wg, const float* __restrict__ bg,
    const float* __restrict__ Wc, const float* __restrict__ bc,
    const short* __restrict__ WpF,
    short* __restrict__ p2dbf, float* __restrict__ cross2d)
{
  constexpr int RS = 296;
  __shared__ short g1S[32 * RS];
  __shared__ short g2S[32 * RS];
  const int tid = threadIdx.x;
  const int lane = tid & 63;
  const int w = tid >> 6;
  const int lm = lane & 15;
  const int quad = lane >> 4;
  const int base = blockIdx.x * 32;

  for (int e = tid; e < 32 * 32; e += 256) {
    int r = e >> 5, cc = 256 + (e & 31);
    if (cc >= CP) {
      g1S[r * RS + cc] = 0;
      g2S[r * RS + cc] = 0;
    }
  }

  {
    const int c = tid;
    float wg[16], wc[16];
    #pragma unroll
    for (int ci = 0; ci < 16; ++ci) {
      wg[ci] = Wg[ci * CP + c];
      wc[ci] = Wc[ci * CP + c];
    }
    const float bgv = bg[c], bcv = bc[c];
    for (int r = 0; r < 32; ++r) {
      const int row = base + r;
      const int idx = nn_idx[row];
      const float* yr = y3d + (size_t)row * C3;
      float f = (idx >= 0) ? f2d[(size_t)idx * CP + c] : 0.f;
      float a1 = bgv, a2 = bcv;
      #pragma unroll
      for (int ci = 0; ci < 16; ++ci) {
        float yv = yr[ci];
        a1 = fmaf(yv, wg[ci], a1);
        a2 = fmaf(yv, wc[ci], a2);
      }
      g1S[r * RS + c] = bf16r(fmaxf(a1, 0.f) * f);
      g2S[r * RS + c] = bf16r(fmaxf(a2, 0.f) * f);
    }
  }
  if (w == 0 && lane < 3) {
    const int c = 256 + lane;
    float wg[16], wc[16];
    #pragma unroll
    for (int ci = 0; ci < 16; ++ci) {
      wg[ci] = Wg[ci * CP + c];
      wc[ci] = Wc[ci * CP + c];
    }
    const float bgv = bg[c], bcv = bc[c];
    for (int r = 0; r < 32; ++r) {
      const int row = base + r;
      const int idx = nn_idx[row];
      const float* yr = y3d + (size_t)row * C3;
      float f = (idx >= 0) ? f2d[(size_t)idx * CP + c] : 0.f;
      float a1 = bgv, a2 = bcv;
      #pragma unroll
      for (int ci = 0; ci < 16; ++ci) {
        float yv = yr[ci];
        a1 = fmaf(yv, wg[ci], a1);
        a2 = fmaf(yv, wc[ci], a2);
      }
      g1S[r * RS + c] = bf16r(fmaxf(a1, 0.f) * f);
      g2S[r * RS + c] = bf16r(fmaxf(a2, 0.f) * f);
    }
  }
  __syncthreads();

  const int gsel = w & 1;
  const int mt = w >> 1;
  const short* gS = gsel ? g2S : g1S;
  f32x4 acc[4];
  #pragma unroll
  for (int t = 0; t < 4; ++t) {
    f32x4 z = {0.f, 0.f, 0.f, 0.f};
    acc[t] = z;
  }
  #pragma unroll
  for (int q = 0; q < 9; ++q) {
    short8 af = *(const short8*)&gS[(mt * 16 + lm) * RS + q * 32 + quad * 8];
    #pragma unroll
    for (int t = 0; t < 4; ++t) {
      short8 bf = *(const short8*)&WpF[(((q * 4 + t) * 64) + lane) * 8];
      acc[t] = __builtin_amdgcn_mfma_f32_16x16x32_bf16(af, bf, acc[t], 0, 0, 0);
    }
  }
  #pragma unroll
  for (int t = 0; t < 4; ++t) {
    const int c = t * 16 + lm;
    #pragma unroll
    for (int rg = 0; rg < 4; ++rg) {
      const int row = base + mt * 16 + quad * 4 + rg;
      float v = acc[t][rg];
      if (gsel == 0)
        p2dbf[(size_t)row * C2 + c] = bf16r(v);
      else
        cross2d[(size_t)row * C2 + c] = v;
    }
  }
}

// ---------------------------------------------------------------------------
// Wave-autonomous no-LDS subm-conv: gather DIRECTLY into MFMA A-fragments.
//
// A-frag layout for mfma_f32_16x16x32_bf16: lane (quad,lm) holds 8 contiguous
// bf16 of row lm at k-offset q*32+quad*8 -> exactly a 16B-aligned slice of the
// gathered row in global memory (chunk ch = q*4+quad).  Each output row is
// consumed by exactly one wave (nbr indices are random -> zero cross-wave
// reuse), so LDS staging bought nothing; dropping it removes both barriers
// and the per-iter vmcnt(0) lockstep drain that made the old kernel
// latency-bound (MfmaUtil 9%, HBM 26%).
//
// Block = 64 threads (1 wave), MT=2 m-tiles (32 rows), depth-3 rotating
// register prefetch (27 = 9*3, clean rotation): ~12-14 gathers in flight per
// wave continuously.  B-fragments straight from fragment-ordered global
// (L1/L2-hot, reused across MT).
//
// Hardened vs round 0: (1) gather base index clamped to 0 so every formed
// address is in-bounds even if the compiler restructures the predication;
// (2) launch_bounds min-waves relaxed 3 -> 2 (VGPR cap 256, no spill risk).
//
// MODE 0: bn_relu -> fp32    MODE 1: bn_relu -> bf16
// MODE 2: relu(bn)+res(stride 64) -> fp32 mix[:,16+c] + bf16 mixbf
// MODE 3: relu(bn+res) -> fp32 + bf16    MODE 4: relu(bn+res) -> bf16
// ---------------------------------------------------------------------------
template <int CIN, int COUT_, int MODE>
__global__ __launch_bounds__(64, 2) void conv_nolds_kernel(
    const short* __restrict__ finbf, const int* __restrict__ nbr, int nrows,
    const short* __restrict__ WbfF, const float* __restrict__ gamma,
    const float* __restrict__ beta, const float* __restrict__ resf,
    float* __restrict__ outf, short* __restrict__ outbf)
{
  constexpr int KC = (CIN + 31) / 32;   // 32-wide k-chunks per row
  constexpr int DCH = CIN / 8;          // real 16B chunks per row
  constexpr int NT = COUT_ / 16;
  constexpr int MT = 2;

  const int lane = threadIdx.x;
  const int lm = lane & 15;
  const int quad = lane >> 4;
  const int base = blockIdx.x * (MT * 16);

  int rrow[MT];
  bool rok[MT];
  #pragma unroll
  for (int i = 0; i < MT; ++i) {
    rrow[i] = base + i * 16 + lm;
    rok[i] = rrow[i] < nrows;
  }

  f32x4 acc[MT][NT];
  #pragma unroll
  for (int i = 0; i < MT; ++i)
    #pragma unroll
    for (int t = 0; t < NT; ++t) {
      f32x4 z = {0.f, 0.f, 0.f, 0.f};
      acc[i][t] = z;
    }

  const short8 zero8 = {0, 0, 0, 0, 0, 0, 0, 0};

  // neighbor-index load (stride-27 across lm; L1-hot after k=0; 4 quads share)
  auto loadIdx = [&](int (&id)[MT], int k) {
    #pragma unroll
    for (int i = 0; i < MT; ++i)
      id[i] = (k < KOFF && rok[i]) ? nbr[(size_t)rrow[i] * KOFF + k] : -1;
  };

  // gather one k-offset's A-fragments straight from global
  auto loadA = [&](short8 (&pa)[MT][KC], const int (&id)[MT]) {
    #pragma unroll
    for (int i = 0; i < MT; ++i) {
      const int safe = (id[i] < 0) ? 0 : id[i];     // in-bounds address always
      const bool ok = id[i] >= 0;
      const short* src = finbf + (size_t)safe * CIN;
      #pragma unroll
      for (int q = 0; q < KC; ++q) {
        const int ch = q * 4 + quad;
        short8 v = zero8;
        if (ch < DCH) v = *(const short8*)(src + ch * 8);
        pa[i][q] = ok ? v : zero8;
      }
    }
  };

  auto computeK = [&](const short8 (&pa)[MT][KC], int k) {
    const short* wb = WbfF + ((size_t)k * KC * NT) * 512 + lane * 8;
    #pragma unroll
    for (int q = 0; q < KC; ++q) {
      #pragma unroll
      for (int t = 0; t < NT; ++t) {
        short8 bfr = *(const short8*)(wb + (q * NT + t) * 512);
        #pragma unroll
        for (int i = 0; i < MT; ++i)
          acc[i][t] = __builtin_amdgcn_mfma_f32_16x16x32_bf16(pa[i][q], bfr,
                                                              acc[i][t], 0, 0, 0);
      }
    }
  };

  // ---- depth-3 software pipeline over k (27 = 9*3, no tail) ----
  int ia[MT], ib[MT], ic[MT];
  short8 paA[MT][KC], paB[MT][KC], paC[MT][KC];

  loadIdx(ia, 0); loadIdx(ib, 1); loadIdx(ic, 2);
  loadA(paA, ia); loadIdx(ia, 3);
  loadA(paB, ib); loadIdx(ib, 4);

  for (int kk = 0; kk < KOFF; kk += 3) {
    loadA(paC, ic); loadIdx(ic, kk + 5);
    computeK(paA, kk);
    loadA(paA, ia); loadIdx(ia, kk + 6);   // A(kk+3); k>=27 -> idx=-1 -> zeros
    computeK(paB, kk + 1);
    loadA(paB, ib); loadIdx(ib, kk + 7);   // A(kk+4)
    computeK(paC, kk + 2);
  }

  // ---- epilogue ----
  #pragma unroll
  for (int i = 0; i < MT; ++i) {
    int rbase = base + i * 16 + quad * 4;
    #pragma unroll
    for (int t = 0; t < NT; ++t) {
      int c = t * 16 + lm;
      float g = gamma[c], b = beta[c];
      #pragma unroll
      for (int rg = 0; rg < 4; ++rg) {
        int row = rbase + rg;
        if (row >= nrows) continue;
        float v = acc[i][t][rg];
        if (MODE == 0) {
          outf[(size_t)row * COUT_ + c] = fmaxf(fmaf(v, g, b), 0.f);
        } else if (MODE == 1) {
          outbf[(size_t)row * COUT_ + c] = bf16r(fmaxf(fmaf(v, g, b), 0.f));
        } else if (MODE == 2) {
          float o = fmaxf(fmaf(v, g, b), 0.f) + resf[(size_t)row * C2 + c];
          outf[(size_t)row * CM + 16 + c] = o;
          outbf[(size_t)row * CM + 16 + c] = bf16r(o);
        } else if (MODE == 3) {
          float o = fmaxf(fmaf(v, g, b) + resf[(size_t)row * COUT_ + c], 0.f);
          outf[(size_t)row * COUT_ + c] = o;
          outbf[(size_t)row * COUT_ + c] = bf16r(o);
        } else {
          float o = fmaxf(fmaf(v, g, b) + resf[(size_t)row * COUT_ + c], 0.f);
          outbf[(size_t)row * COUT_ + c] = bf16r(o);
        }
      }
    }
  }
}

// ---------------------------------------------------------------------------
extern "C" void kernel_launch(void* const* d_in, const int* in_sizes, int n_in,
                              void* d_out, int out_size, void* d_ws, size_t ws_size,
                              hipStream_t stream) {
  const float* x3d  = (const float*)d_in[0];
  const float* f2d  = (const float*)d_in[1];
  const int*   nn   = (const int*)d_in[2];
  const int*   nbr  = (const int*)d_in[3];
  const int*   nbds = (const int*)d_in[4];
  const float* W3d  = (const float*)d_in[5];
  const float* g3d  = (const float*)d_in[6];
  const float* b3d  = (const float*)d_in[7];
  const float* Wg   = (const float*)d_in[8];
  const float* bg   = (const float*)d_in[9];
  const float* Wc   = (const float*)d_in[10];
  const float* bc   = (const float*)d_in[11];
  const float* Wp   = (const float*)d_in[12];
  const float* W2d  = (const float*)d_in[13];
  const float* g2d  = (const float*)d_in[14];
  const float* b2d  = (const float*)d_in[15];
  const float* Wm1  = (const float*)d_in[16];
  const float* gm1  = (const float*)d_in[17];
  const float* bm1  = (const float*)d_in[18];
  const float* Wm2  = (const float*)d_in[19];
  const float* gm2  = (const float*)d_in[20];
  const float* bm2  = (const float*)d_in[21];
  const float* Wa1  = (const float*)d_in[22];
  const float* ga1  = (const float*)d_in[23];
  const float* ba1  = (const float*)d_in[24];
  const float* Wa2  = (const float*)d_in[25];
  const float* ga2  = (const float*)d_in[26];
  const float* ba2  = (const float*)d_in[27];
  const float* Wds  = (const float*)d_in[28];
  const float* gds  = (const float*)d_in[29];
  const float* bds  = (const float*)d_in[30];

  const size_t N = NPTS;
  float* ws = (float*)d_ws;
  float* y3d     = ws;                    // N*16
  short* p2dbf   = (short*)(ws + N * 16); // N*64 bf16
  float* cross2d = ws + N * 48;           // N*64
  float* mix     = ws + N * 112;          // N*80
  short* mixbf   = (short*)(ws + N * 192);// N*80 bf16
  short* tmp1bf  = (short*)(ws + N * 232);// N*80 bf16
  float* hbuf    = ws + N * 272;          // N*80
  short* hbufbf  = (short*)(ws + N * 352);// N*80 bf16
  short* abufbf  = (short*)ws;            // N*80 bf16 (reuses y3d+p2dbf)
  // fragment-ordered bf16 weights at tail
  short* wtail  = (short*)(ws + N * 392);
  short* WbfF2d = wtail;                   // 27*2*4*512 = 110592
  short* WbfFm1 = WbfF2d + 110592;         // 27*3*5*512 = 207360
  short* WbfFm2 = WbfFm1 + 207360;
  short* WbfFa1 = WbfFm2 + 207360;
  short* WbfFa2 = WbfFa1 + 207360;
  short* WbfFds = WbfFa2 + 207360;         // 27*3*6*512 = 248832
  short* WpF    = WbfFds + 248832;         // 18432

  // ---- weight prep ----
  wfrag_kernel<<<(110592 + 255) / 256, 256, 0, stream>>>(W2d, WbfF2d, 64, 64, 2);
  wfrag_kernel<<<(207360 + 255) / 256, 256, 0, stream>>>(Wm1, WbfFm1, 80, 80, 3);
  wfrag_kernel<<<(207360 + 255) / 256, 256, 0, stream>>>(Wm2, WbfFm2, 80, 80, 3);
  wfrag_kernel<<<(207360 + 255) / 256, 256, 0, stream>>>(Wa1, WbfFa1, 80, 80, 3);
  wfrag_kernel<<<(207360 + 255) / 256, 256, 0, stream>>>(Wa2, WbfFa2, 80, 80, 3);
  wfrag_kernel<<<(248832 + 255) / 256, 256, 0, stream>>>(Wds, WbfFds, 80, 96, 3);
  wpfrag_kernel<<<(9 * 4 * 64 * 8 + 255) / 256, 256, 0, stream>>>(Wp, WpF);

  conv3d_bnrelu_kernel<<<NPTS / 16, 256, 0, stream>>>(x3d, nbr, W3d, g3d, b3d,
                                                      y3d, mix, mixbf);
  gate_cross_mfma_kernel<<<NPTS / 32, 256, 0, stream>>>(y3d, f2d, nn, Wg, bg,
                                                        Wc, bc, WpF, p2dbf,
                                                        cross2d);

  const int gridW = (NPTS + 31) / 32;    // 2500 one-wave blocks
  conv_nolds_kernel<64, 64, 2><<<gridW, 64, 0, stream>>>(
      p2dbf, nbr, NPTS, WbfF2d, g2d, b2d, cross2d, mix, mixbf);
  conv_nolds_kernel<80, 80, 1><<<gridW, 64, 0, stream>>>(
      mixbf, nbr, NPTS, WbfFm1, gm1, bm1, nullptr, nullptr, tmp1bf);
  conv_nolds_kernel<80, 80, 3><<<gridW, 64, 0, stream>>>(
      tmp1bf, nbr, NPTS, WbfFm2, gm2, bm2, mix, hbuf, hbufbf);
  conv_nolds_kernel<80, 80, 1><<<gridW, 64, 0, stream>>>(
      hbufbf, nbr, NPTS, WbfFa1, ga1, ba1, nullptr, nullptr, tmp1bf);
  conv_nolds_kernel<80, 80, 4><<<gridW, 64, 0, stream>>>(
      tmp1bf, nbr, NPTS, WbfFa2, ga2, ba2, hbuf, nullptr, abufbf);

  const int gridDS = (NDPTS + 31) / 32;  // 313
  conv_nolds_kernel<80, 96, 0><<<gridDS, 64, 0, stream>>>(
      abufbf, nbds, NDPTS, WbfFds, gds, bds, nullptr, (float*)d_out, nullptr);
}